// Round 4
// baseline (202.921 us; speedup 1.0000x reference)
//
#include <hip/hip_runtime.h>
#include <math.h>

#define BB   16
#define CC   4
#define HH   640
#define WW   640
#define HWSZ (HH*WW)        // 409600 pixels per image
#define KM   16             // labels 1..16 tracked; 0 = background (dummy slot)
#define NSUM (KM*CC)        // 64 channel-sum slots per image
#define NACC (NSUM+KM)      // + 16 counts = 80 ws floats per image
#define SIGMA_D 3.0f

#define NWAVE 4             // waves per block (256 threads)
#define NSUB  16            // sub-histograms per wave: one per lane-quad
#define SLOTS 85            // 17 labels x 5 (4 ch sums + count)
#define SUBP  89            // padded stride; 89%32=25 (odd) -> 16 quad bases on 16 distinct banks
#define WAVEP (NSUB*SUBP)   // 1424 floats per wave; total LDS = 4*1424*4B = 22784 B

// ---------------------------------------------------------------------------
// Kernel 1: per-(image,label) channel sums + counts via LDS float atomics
// into PER-LANE-QUAD sub-histograms. Round-3 lesson: one histogram per wave
// put ~3.8-way same-address + heavy same-bank collisions on every ds_add
// (~200 cyc/inst, kernel 100% LDS-atomic-bound at 190us). 64 copies per
// block decorrelate addresses: ~1.1-way same-address, ~2-way banks (free).
// grid = (64, B), block = 256.
// ---------------------------------------------------------------------------
__global__ __launch_bounds__(256) void seg_kernel(
    const float* __restrict__ pred, const int* __restrict__ labels,
    float* __restrict__ ws)
{
    const int b    = blockIdx.y;
    const int t    = threadIdx.x;
    const int wave = t >> 6;
    const int quad = (t >> 2) & (NSUB - 1);

    __shared__ float sacc[NWAVE * WAVEP];
    for (int i = t; i < NWAVE * WAVEP; i += 256) sacc[i] = 0.f;
    __syncthreads();

    float* my = sacc + wave * WAVEP + quad * SUBP;

    const int4*   lab = (const int4*)(labels + (size_t)b * HWSZ);
    const float4* p0  = (const float4*)(pred + ((size_t)b * CC + 0) * HWSZ);
    const float4* p1  = (const float4*)(pred + ((size_t)b * CC + 1) * HWSZ);
    const float4* p2  = (const float4*)(pred + ((size_t)b * CC + 2) * HWSZ);
    const float4* p3  = (const float4*)(pred + ((size_t)b * CC + 3) * HWSZ);

    const int NGROUPS = HWSZ / 4;          // 102400 float4-groups per image
    const int STRIDE  = gridDim.x * 256;

    for (int g = blockIdx.x * 256 + t; g < NGROUPS; g += STRIDE) {
        int4   L  = lab[g];
        float4 v0 = p0[g], v1 = p1[g], v2 = p2[g], v3 = p3[g];
        {   // pixel 0
            float* s = my + L.x * 5;
            atomicAdd(s + 0, v0.x); atomicAdd(s + 1, v1.x);
            atomicAdd(s + 2, v2.x); atomicAdd(s + 3, v3.x);
            atomicAdd(s + 4, 1.0f);
        }
        {   // pixel 1
            float* s = my + L.y * 5;
            atomicAdd(s + 0, v0.y); atomicAdd(s + 1, v1.y);
            atomicAdd(s + 2, v2.y); atomicAdd(s + 3, v3.y);
            atomicAdd(s + 4, 1.0f);
        }
        {   // pixel 2
            float* s = my + L.z * 5;
            atomicAdd(s + 0, v0.z); atomicAdd(s + 1, v1.z);
            atomicAdd(s + 2, v2.z); atomicAdd(s + 3, v3.z);
            atomicAdd(s + 4, 1.0f);
        }
        {   // pixel 3
            float* s = my + L.w * 5;
            atomicAdd(s + 0, v0.w); atomicAdd(s + 1, v1.w);
            atomicAdd(s + 2, v2.w); atomicAdd(s + 3, v3.w);
            atomicAdd(s + 4, 1.0f);
        }
    }
    __syncthreads();

    // fold the 64 sub-histograms; threads 5..84 scatter labels 1..16 to ws
    if (t < SLOTS) {
        float v = 0.f;
        #pragma unroll 8
        for (int c = 0; c < NWAVE * NSUB; ++c) v += sacc[c * SUBP + t];
        if (t >= 5) {
            int lb = t / 5;                   // 1..16
            int cc = t - lb * 5;              // 0..4
            int idx = (cc < 4) ? ((lb - 1) * 4 + cc) : (NSUM + (lb - 1));
            atomicAdd(&ws[b * NACC + idx], v);
        }
    }
}

// ---------------------------------------------------------------------------
// Kernel 2: tiny epilogue — N, f, sum_g, Kb, own/other/scale, scalar out.
// ---------------------------------------------------------------------------
__global__ void finalize_kernel(const float* __restrict__ ws, float* __restrict__ out)
{
    __shared__ float s_sumg[BB], s_P[BB], s_Kb[BB];
    const float F0 = logf(SIGMA_D * SIGMA_D + 1.0f);   // log(10)
    int b = threadIdx.x;
    if (b < BB) {
        const float* w = ws + b * NACC;
        float cnt_sum = 0.f, sum_g = 0.f, Kb = 0.f;
        for (int k = 1; k <= KM; ++k) {
            float s0 = w[(k-1)*4+0], s1 = w[(k-1)*4+1];
            float s2 = w[(k-1)*4+2], s3 = w[(k-1)*4+3];
            float cn = w[NSUM + (k-1)];
            float N  = sqrtf(s0*s0 + s1*s1 + s2*s2 + s3*s3);
            float r  = fmaxf(SIGMA_D - N, 0.f);
            float f  = logf(r*r + 1.0f);
            sum_g   += cn * f;
            cnt_sum += cn;
            if (cn > 0.f) Kb = (float)k;
        }
        float c0 = (float)HWSZ - cnt_sum;     // background count
        sum_g += c0 * F0;
        s_sumg[b] = sum_g;
        s_Kb[b]   = Kb;
        s_P[b]    = (Kb > 1.f) ? Kb * (Kb - 1.f) * 0.5f : 0.f;  // P_act
    }
    __syncthreads();
    if (threadIdx.x == 0) {
        double sumP = 0.0;
        for (int i = 0; i < BB; ++i) sumP += (double)s_P[i];
        double total = 0.0;
        for (int i = 0; i < BB; ++i) {
            double Kb   = (double)s_Kb[i];
            double Pact = (double)s_P[i];
            double own  = 0.0;
            if (Kb > 1.0)
                own = (Kb - 1.0) * (double)s_sumg[i]
                    + (double)HWSZ * (Pact - (Kb - 1.0)) * (double)F0;
            double other = (sumP - Pact) * (double)HWSZ * (double)F0;
            double scale = (Kb > 1.0) ? 1.0 / (Kb * (Kb - 1.0)) : Kb;
            total += scale * (own + other);
        }
        out[0] = (float)total;
    }
}

// ---------------------------------------------------------------------------
extern "C" void kernel_launch(void* const* d_in, const int* in_sizes, int n_in,
                              void* d_out, int out_size, void* d_ws, size_t ws_size,
                              hipStream_t stream)
{
    const float* pred   = (const float*)d_in[0];
    const int*   labels = (const int*)d_in[1];
    float*       out    = (float*)d_out;
    float*       ws     = (float*)d_ws;

    hipMemsetAsync(ws, 0, BB * NACC * sizeof(float), stream);

    dim3 grid(64, BB);
    seg_kernel<<<grid, 256, 0, stream>>>(pred, labels, ws);
    finalize_kernel<<<1, 64, 0, stream>>>(ws, out);
}

// Round 5
// 147.274 us; speedup vs baseline: 1.3778x; 1.3778x over previous
//
#include <hip/hip_runtime.h>
#include <math.h>

#define BB   16
#define CC   4
#define HH   640
#define WW   640
#define HWSZ (HH*WW)        // 409600 pixels per image
#define KM   16             // labels 1..16; 0 = background (derived)
#define NSUM (KM*CC)        // 64 channel-sum slots per image
#define NACC (NSUM+KM)      // + 16 counts = 80 ws floats per image
#define SIGMA_D 3.0f
#define GX   128            // blocks per image

// ---------------------------------------------------------------------------
// Kernel 1: per-(image,label) channel sums + counts, pure-register histogram
// with PER-WAVE LABEL SPLIT. Lessons: LDS atomics = ~224cyc/inst fixed
// (rounds 3-4, conflict-independent); >64 per-thread accumulators spill
// (rounds 1-2). Here each wave owns 4 labels -> 20 statically-indexed
// accumulators/thread (~55 VGPR). All 4 waves scan the block's same groups
// (L1/L2 serves the re-reads; HBM reads each byte once).
// grid = (GX, B), block = 256.
// ---------------------------------------------------------------------------
__global__ __launch_bounds__(256) void seg_kernel(
    const float* __restrict__ pred, const int* __restrict__ labels,
    float* __restrict__ ws)
{
    const int b     = blockIdx.y;
    const int t     = threadIdx.x;
    const int lane  = t & 63;
    const int w     = t >> 6;          // wave id 0..3
    const int kbase = w * 4 + 1;       // this wave's labels: kbase..kbase+3

    const int4*   lab = (const int4*)(labels + (size_t)b * HWSZ);
    const float4* p0  = (const float4*)(pred + ((size_t)b * CC + 0) * HWSZ);
    const float4* p1  = (const float4*)(pred + ((size_t)b * CC + 1) * HWSZ);
    const float4* p2  = (const float4*)(pred + ((size_t)b * CC + 2) * HWSZ);
    const float4* p3  = (const float4*)(pred + ((size_t)b * CC + 3) * HWSZ);

    const int NG  = HWSZ / 4;          // 102400 float4-groups per image
    const int STR = 64 * GX;           // group stride (all waves same groups)

    float acc[4][4];                   // [label][channel]
    float cnt[4];
    #pragma unroll
    for (int kk = 0; kk < 4; ++kk) {
        cnt[kk] = 0.f;
        #pragma unroll
        for (int c = 0; c < CC; ++c) acc[kk][c] = 0.f;
    }

    for (int g = blockIdx.x * 64 + lane; g < NG; g += STR) {
        int4   L  = lab[g];
        float4 v0 = p0[g], v1 = p1[g], v2 = p2[g], v3 = p3[g];
        int   lb[4]    = {L.x, L.y, L.z, L.w};
        float a[4][4]  = {{v0.x, v1.x, v2.x, v3.x},
                          {v0.y, v1.y, v2.y, v3.y},
                          {v0.z, v1.z, v2.z, v3.z},
                          {v0.w, v1.w, v2.w, v3.w}};   // a[pixel][channel]
        #pragma unroll
        for (int kk = 0; kk < 4; ++kk) {
            const int k = kbase + kk;
            #pragma unroll
            for (int j = 0; j < 4; ++j) {
                float m = (lb[j] == k) ? 1.0f : 0.0f;
                acc[kk][0] = fmaf(m, a[j][0], acc[kk][0]);
                acc[kk][1] = fmaf(m, a[j][1], acc[kk][1]);
                acc[kk][2] = fmaf(m, a[j][2], acc[kk][2]);
                acc[kk][3] = fmaf(m, a[j][3], acc[kk][3]);
                cnt[kk]   += m;
            }
        }
    }

    // wave butterfly reduce (all indices static), lane 0 scatters to ws
    #pragma unroll
    for (int kk = 0; kk < 4; ++kk) {
        #pragma unroll
        for (int c = 0; c < CC; ++c) {
            float v = acc[kk][c];
            v += __shfl_xor(v, 1);  v += __shfl_xor(v, 2);
            v += __shfl_xor(v, 4);  v += __shfl_xor(v, 8);
            v += __shfl_xor(v, 16); v += __shfl_xor(v, 32);
            acc[kk][c] = v;
        }
        float v = cnt[kk];
        v += __shfl_xor(v, 1);  v += __shfl_xor(v, 2);
        v += __shfl_xor(v, 4);  v += __shfl_xor(v, 8);
        v += __shfl_xor(v, 16); v += __shfl_xor(v, 32);
        cnt[kk] = v;
    }

    if (lane == 0) {
        float* wsb = ws + b * NACC;
        #pragma unroll
        for (int kk = 0; kk < 4; ++kk) {
            const int kidx = kbase - 1 + kk;       // 0..15
            #pragma unroll
            for (int c = 0; c < CC; ++c)
                atomicAdd(&wsb[kidx * 4 + c], acc[kk][c]);
            atomicAdd(&wsb[NSUM + kidx], cnt[kk]);
        }
    }
}

// ---------------------------------------------------------------------------
// Kernel 2: tiny epilogue — N, f, sum_g, Kb, own/other/scale, scalar out.
// ---------------------------------------------------------------------------
__global__ void finalize_kernel(const float* __restrict__ ws, float* __restrict__ out)
{
    __shared__ float s_sumg[BB], s_P[BB], s_Kb[BB];
    const float F0 = logf(SIGMA_D * SIGMA_D + 1.0f);   // log(10)
    int b = threadIdx.x;
    if (b < BB) {
        const float* w = ws + b * NACC;
        float cnt_sum = 0.f, sum_g = 0.f, Kb = 0.f;
        for (int k = 1; k <= KM; ++k) {
            float s0 = w[(k-1)*4+0], s1 = w[(k-1)*4+1];
            float s2 = w[(k-1)*4+2], s3 = w[(k-1)*4+3];
            float cn = w[NSUM + (k-1)];
            float N  = sqrtf(s0*s0 + s1*s1 + s2*s2 + s3*s3);
            float r  = fmaxf(SIGMA_D - N, 0.f);
            float f  = logf(r*r + 1.0f);
            sum_g   += cn * f;
            cnt_sum += cn;
            if (cn > 0.f) Kb = (float)k;
        }
        float c0 = (float)HWSZ - cnt_sum;     // background count
        sum_g += c0 * F0;
        s_sumg[b] = sum_g;
        s_Kb[b]   = Kb;
        s_P[b]    = (Kb > 1.f) ? Kb * (Kb - 1.f) * 0.5f : 0.f;  // P_act
    }
    __syncthreads();
    if (threadIdx.x == 0) {
        double sumP = 0.0;
        for (int i = 0; i < BB; ++i) sumP += (double)s_P[i];
        double total = 0.0;
        for (int i = 0; i < BB; ++i) {
            double Kb   = (double)s_Kb[i];
            double Pact = (double)s_P[i];
            double own  = 0.0;
            if (Kb > 1.0)
                own = (Kb - 1.0) * (double)s_sumg[i]
                    + (double)HWSZ * (Pact - (Kb - 1.0)) * (double)F0;
            double other = (sumP - Pact) * (double)HWSZ * (double)F0;
            double scale = (Kb > 1.0) ? 1.0 / (Kb * (Kb - 1.0)) : Kb;
            total += scale * (own + other);
        }
        out[0] = (float)total;
    }
}

// ---------------------------------------------------------------------------
extern "C" void kernel_launch(void* const* d_in, const int* in_sizes, int n_in,
                              void* d_out, int out_size, void* d_ws, size_t ws_size,
                              hipStream_t stream)
{
    const float* pred   = (const float*)d_in[0];
    const int*   labels = (const int*)d_in[1];
    float*       out    = (float*)d_out;
    float*       ws     = (float*)d_ws;

    hipMemsetAsync(ws, 0, BB * NACC * sizeof(float), stream);

    dim3 grid(GX, BB);
    seg_kernel<<<grid, 256, 0, stream>>>(pred, labels, ws);
    finalize_kernel<<<1, 64, 0, stream>>>(ws, out);
}

// Round 6
// 90.295 us; speedup vs baseline: 2.2473x; 1.6310x over previous
//
#include <hip/hip_runtime.h>
#include <math.h>
#include <stdint.h>

#define BB   16
#define CC   4
#define HH   640
#define WW   640
#define HWSZ (HH*WW)        // 409600 pixels per image
#define KM   16             // labels 1..16; 0 = background (derived)
#define NSUM (KM*CC)        // 64 channel-sum slots per image
#define NACC (NSUM+KM)      // + 16 counts = 80 ws floats per image
#define SIGMA_D 3.0f

#define TG   256            // int4/float4 groups per tile (=1024 pixels)
#define NT   (HWSZ/4/TG)    // 400 tiles per image
#define GXB  64             // blocks per image -> 1024 blocks, 4/CU (LDS-limited)

// ---------------------------------------------------------------------------
// Kernel 1: per-(image,label) channel sums + counts.
// LDS-staged tiles (global_load_lds width=16, double-buffered) + per-wave
// label split. Lessons so far: LDS atomics ~224cyc/inst regardless of
// conflicts (r3/r4); >64 register accumulators spill (r1/r2); 4-wave global
// re-read + 13 dependent iters = latency-bound 147us (r5). Here: global
// traffic exactly 1x, re-read served by LDS (69 TB/s), prefetch always in
// flight, 20 statically-indexed accumulators/thread (no spill).
// Pipeline per tile: syncthreads (drains last prefetch) -> issue next stage
// -> compute current from LDS. One barrier per tile.
// grid = (GXB, B), block = 256.
// ---------------------------------------------------------------------------
__global__ __launch_bounds__(256) void seg_kernel(
    const float* __restrict__ pred, const int* __restrict__ labels,
    float* __restrict__ ws)
{
    __shared__ int4   s_lab[2][TG];          //  8 KB
    __shared__ float4 s_prd[2][CC][TG];      // 32 KB

    const int b     = blockIdx.y;
    const int t     = threadIdx.x;
    const int lane  = t & 63;
    const int w     = t >> 6;                // wave 0..3
    const int kbase = w * 4 + 1;             // this wave's labels

    const int4*   lab4 = (const int4*)(labels + (size_t)b * HWSZ);
    const float4* pw   = (const float4*)(pred + ((size_t)b * CC + w) * HWSZ); // wave w stages channel w

    float acc[4][4];                         // [label][channel], all static idx
    float cnt[4];
    #pragma unroll
    for (int kk = 0; kk < 4; ++kk) {
        cnt[kk] = 0.f;
        #pragma unroll
        for (int c = 0; c < CC; ++c) acc[kk][c] = 0.f;
    }

    // async stage of one tile into buffer bf: each wave issues 5 x 16B/lane
    // global_load_lds (uniform LDS base + lane*16 linear dest).
    auto STAGE = [&](int bf, int tile) {
        const int g0 = tile * TG;
        __builtin_amdgcn_global_load_lds(
            (const __attribute__((address_space(1))) void*)(lab4 + g0 + w * 64 + lane),
            (__attribute__((address_space(3))) void*)(&s_lab[bf][w * 64]), 16, 0, 0);
        #pragma unroll
        for (int s = 0; s < 4; ++s)
            __builtin_amdgcn_global_load_lds(
                (const __attribute__((address_space(1))) void*)(pw + g0 + s * 64 + lane),
                (__attribute__((address_space(3))) void*)(&s_prd[bf][w][s * 64]), 16, 0, 0);
    };

    int cur = 0;
    STAGE(0, blockIdx.x);
    for (int tile = blockIdx.x; tile < NT; tile += GXB) {
        __syncthreads();                      // drains prefetch (vmcnt 0) + joins waves
        const int nxt = tile + GXB;
        if (nxt < NT) STAGE(cur ^ 1, nxt);    // async prefetch, flies under compute

        #pragma unroll
        for (int it = 0; it < 4; ++it) {
            const int g = it * 64 + lane;
            int4   L  = s_lab[cur][g];
            float4 q0 = s_prd[cur][0][g];
            float4 q1 = s_prd[cur][1][g];
            float4 q2 = s_prd[cur][2][g];
            float4 q3 = s_prd[cur][3][g];
            int   lb[4]    = {L.x, L.y, L.z, L.w};
            float px[4][4] = {{q0.x, q1.x, q2.x, q3.x},
                              {q0.y, q1.y, q2.y, q3.y},
                              {q0.z, q1.z, q2.z, q3.z},
                              {q0.w, q1.w, q2.w, q3.w}};  // [pixel][channel]
            #pragma unroll
            for (int kk = 0; kk < 4; ++kk) {
                const int k = kbase + kk;
                #pragma unroll
                for (int j = 0; j < 4; ++j) {
                    float m = (lb[j] == k) ? 1.0f : 0.0f;
                    acc[kk][0] = fmaf(m, px[j][0], acc[kk][0]);
                    acc[kk][1] = fmaf(m, px[j][1], acc[kk][1]);
                    acc[kk][2] = fmaf(m, px[j][2], acc[kk][2]);
                    acc[kk][3] = fmaf(m, px[j][3], acc[kk][3]);
                    cnt[kk]   += m;
                }
            }
        }
        cur ^= 1;
    }

    // wave butterfly reduce (static indices), lane 0 scatters to ws
    #pragma unroll
    for (int kk = 0; kk < 4; ++kk) {
        #pragma unroll
        for (int c = 0; c < CC; ++c) {
            float v = acc[kk][c];
            v += __shfl_xor(v, 1);  v += __shfl_xor(v, 2);
            v += __shfl_xor(v, 4);  v += __shfl_xor(v, 8);
            v += __shfl_xor(v, 16); v += __shfl_xor(v, 32);
            acc[kk][c] = v;
        }
        float v = cnt[kk];
        v += __shfl_xor(v, 1);  v += __shfl_xor(v, 2);
        v += __shfl_xor(v, 4);  v += __shfl_xor(v, 8);
        v += __shfl_xor(v, 16); v += __shfl_xor(v, 32);
        cnt[kk] = v;
    }

    if (lane == 0) {
        float* wsb = ws + b * NACC;
        #pragma unroll
        for (int kk = 0; kk < 4; ++kk) {
            const int kidx = kbase - 1 + kk;   // 0..15
            #pragma unroll
            for (int c = 0; c < CC; ++c)
                atomicAdd(&wsb[kidx * 4 + c], acc[kk][c]);
            atomicAdd(&wsb[NSUM + kidx], cnt[kk]);
        }
    }
}

// ---------------------------------------------------------------------------
// Kernel 2: tiny epilogue — N, f, sum_g, Kb, own/other/scale, scalar out.
// ---------------------------------------------------------------------------
__global__ void finalize_kernel(const float* __restrict__ ws, float* __restrict__ out)
{
    __shared__ float s_sumg[BB], s_P[BB], s_Kb[BB];
    const float F0 = logf(SIGMA_D * SIGMA_D + 1.0f);   // log(10)
    int b = threadIdx.x;
    if (b < BB) {
        const float* w = ws + b * NACC;
        float cnt_sum = 0.f, sum_g = 0.f, Kb = 0.f;
        for (int k = 1; k <= KM; ++k) {
            float s0 = w[(k-1)*4+0], s1 = w[(k-1)*4+1];
            float s2 = w[(k-1)*4+2], s3 = w[(k-1)*4+3];
            float cn = w[NSUM + (k-1)];
            float N  = sqrtf(s0*s0 + s1*s1 + s2*s2 + s3*s3);
            float r  = fmaxf(SIGMA_D - N, 0.f);
            float f  = logf(r*r + 1.0f);
            sum_g   += cn * f;
            cnt_sum += cn;
            if (cn > 0.f) Kb = (float)k;
        }
        float c0 = (float)HWSZ - cnt_sum;     // background count
        sum_g += c0 * F0;
        s_sumg[b] = sum_g;
        s_Kb[b]   = Kb;
        s_P[b]    = (Kb > 1.f) ? Kb * (Kb - 1.f) * 0.5f : 0.f;  // P_act
    }
    __syncthreads();
    if (threadIdx.x == 0) {
        double sumP = 0.0;
        for (int i = 0; i < BB; ++i) sumP += (double)s_P[i];
        double total = 0.0;
        for (int i = 0; i < BB; ++i) {
            double Kb   = (double)s_Kb[i];
            double Pact = (double)s_P[i];
            double own  = 0.0;
            if (Kb > 1.0)
                own = (Kb - 1.0) * (double)s_sumg[i]
                    + (double)HWSZ * (Pact - (Kb - 1.0)) * (double)F0;
            double other = (sumP - Pact) * (double)HWSZ * (double)F0;
            double scale = (Kb > 1.0) ? 1.0 / (Kb * (Kb - 1.0)) : Kb;
            total += scale * (own + other);
        }
        out[0] = (float)total;
    }
}

// ---------------------------------------------------------------------------
extern "C" void kernel_launch(void* const* d_in, const int* in_sizes, int n_in,
                              void* d_out, int out_size, void* d_ws, size_t ws_size,
                              hipStream_t stream)
{
    const float* pred   = (const float*)d_in[0];
    const int*   labels = (const int*)d_in[1];
    float*       out    = (float*)d_out;
    float*       ws     = (float*)d_ws;

    hipMemsetAsync(ws, 0, BB * NACC * sizeof(float), stream);

    dim3 grid(GXB, BB);
    seg_kernel<<<grid, 256, 0, stream>>>(pred, labels, ws);
    finalize_kernel<<<1, 64, 0, stream>>>(ws, out);
}

// Round 7
// 69.713 us; speedup vs baseline: 2.9108x; 1.2952x over previous
//
#include <hip/hip_runtime.h>
#include <math.h>

#define BB   16
#define CC   4
#define HH   640
#define WW   640
#define HWSZ (HH*WW)        // 409600 pixels per image
#define KM   16             // labels 1..16; 0 = background (derived)
#define NSUM (KM*CC)        // 64 channel-sum slots per image
#define NACC (NSUM+KM)      // + 16 counts = 80 ws floats per image
#define SIGMA_D 3.0f

#define GXB  64             // blocks per image -> 1024 blocks total (4/CU)
#define GPB  (HWSZ/4/GXB)   // 1600 int4-groups per block
#define NIT  (GPB/64)       // 25 wave-iterations, compile-time constant

// ---------------------------------------------------------------------------
// Kernel 1: per-(image,label) channel sums + counts.
// Register-staged, BARRIER-FREE pipeline. Lessons: LDS atomics ~224cyc/inst
// (r3/r4); >64 register accs spill (r1/r2); barrier-gated LDS tiles create
// phase-lockstep bursts -> memory duty-cycled to 1.45 TB/s (r6). Here: no
// __syncthreads in the loop, explicit 1-deep named-A/B register prefetch
// (no runtime-indexed arrays -> no scratch), exact trip count 25, waves
// drift freely so loads stay continuously outstanding on the proven
// global_load_dwordx4 path. Label-split: wave w owns labels w*4+1..w*4+4,
// 20 statically-indexed accumulators. Sibling-wave re-reads are L1-served.
// grid = (GXB, B), block = 256.
// ---------------------------------------------------------------------------
__global__ __launch_bounds__(256) void seg_kernel(
    const float* __restrict__ pred, const int* __restrict__ labels,
    float* __restrict__ ws)
{
    const int b     = blockIdx.y;
    const int t     = threadIdx.x;
    const int lane  = t & 63;
    const int w     = t >> 6;            // wave 0..3
    const int kbase = w * 4 + 1;         // this wave's labels

    const int4*   lab4 = (const int4*)(labels + (size_t)b * HWSZ);
    const float4* p0   = (const float4*)(pred + ((size_t)b * CC + 0) * HWSZ);
    const float4* p1   = (const float4*)(pred + ((size_t)b * CC + 1) * HWSZ);
    const float4* p2   = (const float4*)(pred + ((size_t)b * CC + 2) * HWSZ);
    const float4* p3   = (const float4*)(pred + ((size_t)b * CC + 3) * HWSZ);

    const int G0 = blockIdx.x * GPB + lane;   // this block's group window

    float acc[4][4];                     // [label][channel], static idx only
    float cnt[4];
    #pragma unroll
    for (int kk = 0; kk < 4; ++kk) {
        cnt[kk] = 0.f;
        #pragma unroll
        for (int c = 0; c < CC; ++c) acc[kk][c] = 0.f;
    }

    // one pixel j of a group: mask against this wave's 4 labels, 4ch FMA
#define PIXEL(LB, X0, X1, X2, X3)                                   \
    {                                                               \
        const int lbv = (LB);                                       \
        _Pragma("unroll")                                           \
        for (int kk = 0; kk < 4; ++kk) {                            \
            float m = (lbv == kbase + kk) ? 1.0f : 0.0f;            \
            acc[kk][0] = fmaf(m, (X0), acc[kk][0]);                 \
            acc[kk][1] = fmaf(m, (X1), acc[kk][1]);                 \
            acc[kk][2] = fmaf(m, (X2), acc[kk][2]);                 \
            acc[kk][3] = fmaf(m, (X3), acc[kk][3]);                 \
            cnt[kk]   += m;                                         \
        }                                                           \
    }

#define COMPUTE(L, Q0, Q1, Q2, Q3)                                  \
    PIXEL((L).x, (Q0).x, (Q1).x, (Q2).x, (Q3).x);                   \
    PIXEL((L).y, (Q0).y, (Q1).y, (Q2).y, (Q3).y);                   \
    PIXEL((L).z, (Q0).z, (Q1).z, (Q2).z, (Q3).z);                   \
    PIXEL((L).w, (Q0).w, (Q1).w, (Q2).w, (Q3).w);

    // software pipeline: named A/B register stages, 1-deep prefetch.
    int4   LA = lab4[G0];
    float4 A0 = p0[G0], A1 = p1[G0], A2 = p2[G0], A3 = p3[G0];
    int4   LBv;
    float4 B0, B1, B2, B3;

    #pragma unroll
    for (int it = 0; it < (NIT - 1) / 2; ++it) {       // 12 double-steps
        const int gB = G0 + (2 * it + 1) * 64;
        LBv = lab4[gB]; B0 = p0[gB]; B1 = p1[gB]; B2 = p2[gB]; B3 = p3[gB];
        COMPUTE(LA, A0, A1, A2, A3);
        const int gA = G0 + (2 * it + 2) * 64;
        LA = lab4[gA]; A0 = p0[gA]; A1 = p1[gA]; A2 = p2[gA]; A3 = p3[gA];
        COMPUTE(LBv, B0, B1, B2, B3);
    }
    COMPUTE(LA, A0, A1, A2, A3);                       // iteration 24

    // wave butterfly reduce (static indices), lane 0 scatters to ws
    #pragma unroll
    for (int kk = 0; kk < 4; ++kk) {
        #pragma unroll
        for (int c = 0; c < CC; ++c) {
            float v = acc[kk][c];
            v += __shfl_xor(v, 1);  v += __shfl_xor(v, 2);
            v += __shfl_xor(v, 4);  v += __shfl_xor(v, 8);
            v += __shfl_xor(v, 16); v += __shfl_xor(v, 32);
            acc[kk][c] = v;
        }
        float v = cnt[kk];
        v += __shfl_xor(v, 1);  v += __shfl_xor(v, 2);
        v += __shfl_xor(v, 4);  v += __shfl_xor(v, 8);
        v += __shfl_xor(v, 16); v += __shfl_xor(v, 32);
        cnt[kk] = v;
    }

    if (lane == 0) {
        float* wsb = ws + b * NACC;
        #pragma unroll
        for (int kk = 0; kk < 4; ++kk) {
            const int kidx = kbase - 1 + kk;   // 0..15
            #pragma unroll
            for (int c = 0; c < CC; ++c)
                atomicAdd(&wsb[kidx * 4 + c], acc[kk][c]);
            atomicAdd(&wsb[NSUM + kidx], cnt[kk]);
        }
    }
#undef PIXEL
#undef COMPUTE
}

// ---------------------------------------------------------------------------
// Kernel 2: tiny epilogue — N, f, sum_g, Kb, own/other/scale, scalar out.
// ---------------------------------------------------------------------------
__global__ void finalize_kernel(const float* __restrict__ ws, float* __restrict__ out)
{
    __shared__ float s_sumg[BB], s_P[BB], s_Kb[BB];
    const float F0 = logf(SIGMA_D * SIGMA_D + 1.0f);   // log(10)
    int b = threadIdx.x;
    if (b < BB) {
        const float* w = ws + b * NACC;
        float cnt_sum = 0.f, sum_g = 0.f, Kb = 0.f;
        for (int k = 1; k <= KM; ++k) {
            float s0 = w[(k-1)*4+0], s1 = w[(k-1)*4+1];
            float s2 = w[(k-1)*4+2], s3 = w[(k-1)*4+3];
            float cn = w[NSUM + (k-1)];
            float N  = sqrtf(s0*s0 + s1*s1 + s2*s2 + s3*s3);
            float r  = fmaxf(SIGMA_D - N, 0.f);
            float f  = logf(r*r + 1.0f);
            sum_g   += cn * f;
            cnt_sum += cn;
            if (cn > 0.f) Kb = (float)k;
        }
        float c0 = (float)HWSZ - cnt_sum;     // background count
        sum_g += c0 * F0;
        s_sumg[b] = sum_g;
        s_Kb[b]   = Kb;
        s_P[b]    = (Kb > 1.f) ? Kb * (Kb - 1.f) * 0.5f : 0.f;  // P_act
    }
    __syncthreads();
    if (threadIdx.x == 0) {
        double sumP = 0.0;
        for (int i = 0; i < BB; ++i) sumP += (double)s_P[i];
        double total = 0.0;
        for (int i = 0; i < BB; ++i) {
            double Kb   = (double)s_Kb[i];
            double Pact = (double)s_P[i];
            double own  = 0.0;
            if (Kb > 1.0)
                own = (Kb - 1.0) * (double)s_sumg[i]
                    + (double)HWSZ * (Pact - (Kb - 1.0)) * (double)F0;
            double other = (sumP - Pact) * (double)HWSZ * (double)F0;
            double scale = (Kb > 1.0) ? 1.0 / (Kb * (Kb - 1.0)) : Kb;
            total += scale * (own + other);
        }
        out[0] = (float)total;
    }
}

// ---------------------------------------------------------------------------
extern "C" void kernel_launch(void* const* d_in, const int* in_sizes, int n_in,
                              void* d_out, int out_size, void* d_ws, size_t ws_size,
                              hipStream_t stream)
{
    const float* pred   = (const float*)d_in[0];
    const int*   labels = (const int*)d_in[1];
    float*       out    = (float*)d_out;
    float*       ws     = (float*)d_ws;

    hipMemsetAsync(ws, 0, BB * NACC * sizeof(float), stream);

    dim3 grid(GXB, BB);
    seg_kernel<<<grid, 256, 0, stream>>>(pred, labels, ws);
    finalize_kernel<<<1, 64, 0, stream>>>(ws, out);
}